// Round 13
// baseline (1204.700 us; speedup 1.0000x reference)
//
#include <hip/hip_runtime.h>
#include <hip/hip_fp16.h>

#define TEMP 8.0f
#define MSHIFT 8.0f   // constant softmax shift; scores in [0,8) so exp in (e^-8, 1]
#define KDIM 8
#define BKT_SHIFT 7                 // 128 nodes per dst-bucket
#define BKT_NODES (1 << BKT_SHIFT)
#define MAXNB 1024                  // bucket arrays (N <= 131072)
#define TILE 3072                   // edges per partition tile (LDS-sorted)
#define PTHR 512
#define EPT 6                       // TILE / PTHR
#define BPT 2                       // MAXNB / PTHR buckets per thread in scan
#define EPB_H 8192                  // edges per histogram block
#define SRC_MASK 0x7FFFFFu          // src8 < 2^20; dib packed at bit 23
// Evidence ledger (r3-r12):
//  - r10/r11/r12: LDS tile-sort + lane-coalesced flush + 2blk/CU: partition
//    106->92->83us. Merging must happen AT ISSUE (within the wave instr).
//  - r12: 6-slot CSR agg ran <=82us, BELOW the old "97us gather floor" ->
//    the 33G lines/s model was latency x outstanding, not a hard cap.
//    Concurrency keeps paying.
//  - r12 decomposition: fine ~80 + agg ~80 = 160us, half of it a pure 51MB
//    payload write + 51MB re-read. THIS ROUND: fuse fine+agg into per-bucket
//    agg with LDS float accumulators (acc[128][8][6] = 24KB, ds_add_f32 is
//    lane-parallel ~20us chip-wide). Payload/deg/offs/dib arrays DELETED
//    (dib packs into payload.w bits 23+). 4 blk/CU for gather latency hiding.
//  - r8: L2-resident table no help -> request slots, not DRAM. r7: unstaged
//    partition regressed. NT/padding/splits/LLC-fit: all null.

__device__ __forceinline__ unsigned pack_h2(float a, float b) {
    __half2 h = __floats2half2_rn(a, b);
    return __builtin_bit_cast(unsigned, h);
}
__device__ __forceinline__ float2 unpack_h2(unsigned v) {
    __half2 h = __builtin_bit_cast(__half2, v);
    return __half22float2(h);
}

__device__ __forceinline__ unsigned long long pack_ql(float4 q, float l) {
    int lu = __float2int_rn(l * 4095.0f);
    lu = lu < 0 ? 0 : (lu > 4095 ? 4095 : lu);
    int vw = __float2int_rn(q.x * 4095.0f);
    int vx = __float2int_rn(q.y * 4095.0f);
    int vy = __float2int_rn(q.z * 4095.0f);
    int vz = __float2int_rn(q.w * 4095.0f);
    return (unsigned long long)(unsigned)lu
         | ((unsigned long long)((unsigned)vw & 0x1FFFu) << 12)
         | ((unsigned long long)((unsigned)vx & 0x1FFFu) << 25)
         | ((unsigned long long)((unsigned)vy & 0x1FFFu) << 38)
         | ((unsigned long long)((unsigned)vz & 0x1FFFu) << 51);
}

__device__ __forceinline__ int sext13(unsigned v) {
    return ((int)(v << 19)) >> 19;
}

// ===== K1: blocks [0,gN) build qltab; blocks [gN,..) LDS-histogram buckets =====
__global__ void prep_hist(const float* __restrict__ levels,
                          const float4* __restrict__ node_q,
                          unsigned long long* __restrict__ qltab, int NK, int gN,
                          const int* __restrict__ edst,
                          int* __restrict__ ghist, int E) {
    __shared__ int h[MAXNB];
    if ((int)blockIdx.x < gN) {
        int i = blockIdx.x * blockDim.x + threadIdx.x;
        if (i >= NK) return;
        qltab[i] = pack_ql(node_q[i], levels[i]);
    } else {
        int tid = threadIdx.x;
        for (int i = tid; i < MAXNB; i += 256) h[i] = 0;
        __syncthreads();
        int beg = (blockIdx.x - gN) * EPB_H;
        int end = beg + EPB_H; if (end > E) end = E;
        for (int e = beg + tid; e < end; e += 256)
            atomicAdd(&h[edst[e] >> BKT_SHIFT], 1);
        __syncthreads();
        for (int i = tid; i < MAXNB; i += 256)
            if (h[i]) atomicAdd(&ghist[i], h[i]);   // non-returning, L2-hot
    }
}

// ===== K2: exclusive scan of bucket counts (1 block, 1024 thr) =====
__global__ void scan_buckets(const int* __restrict__ ghist,
                             int* __restrict__ gbase,
                             int* __restrict__ gcursor, int NBKT, int E) {
    __shared__ int s[1024];
    __shared__ int carry_s;
    int tid = threadIdx.x;
    if (tid == 0) carry_s = 0;
    __syncthreads();
    for (int base = 0; base < MAXNB; base += 1024) {
        int idx = base + tid;
        int v = (idx < NBKT) ? ghist[idx] : 0;
        s[tid] = v;
        __syncthreads();
        for (int off = 1; off < 1024; off <<= 1) {
            int t = (tid >= off) ? s[tid - off] : 0;
            __syncthreads();
            s[tid] += t;
            __syncthreads();
        }
        if (idx < NBKT) {
            int b = s[tid] - v + carry_s;
            gbase[idx] = b;
            gcursor[idx] = b;
        }
        __syncthreads();
        if (tid == 0) carry_s += s[1023];
        __syncthreads();
    }
    if (tid == 0) gbase[NBKT] = E;
}

// ===== K3: LDS tile-sort partition, lane-coalesced flush (~65KB, 2 blk/CU) =====
// ebuf entry 16B = { rel_q 4xfp16, TEMP*w f32, (src*8)|(dib<<23) }
__global__ void __launch_bounds__(PTHR, 4)
partition_lds(const int* __restrict__ edst,
              const int* __restrict__ esrc,
              const float* __restrict__ ew,
              const float4* __restrict__ rel_q,
              int* __restrict__ gcursor,
              float4* __restrict__ ebuf, int E) {
    __shared__ float4 sortbuf[TILE];          // 48 KB
    __shared__ unsigned short sbk[TILE];      // 6 KB: bucket id per position
    __shared__ int cnt[MAXNB];                // 4 KB
    __shared__ int base[MAXNB];               // 4 KB
    __shared__ int gpos[MAXNB];               // 4 KB
    __shared__ int ts[PTHR];                  // 2 KB     (total ~68 KB)

    int tid = threadIdx.x;
    int tbeg = blockIdx.x * TILE;
    int tcnt = E - tbeg; if (tcnt > TILE) tcnt = TILE;

    for (int i = tid; i < MAXNB; i += PTHR) cnt[i] = 0;
    __syncthreads();

    // phase 1: count, remember (bucket, rank, dib) per edge
    int eb[EPT]; int er[EPT]; unsigned char ed[EPT]; bool ev[EPT];
#pragma unroll
    for (int i = 0; i < EPT; ++i) {
        int e = tbeg + i * PTHR + tid;
        ev[i] = (e < E);
        if (ev[i]) {
            int d = edst[e];
            eb[i] = d >> BKT_SHIFT;
            ed[i] = (unsigned char)(d & (BKT_NODES - 1));
            er[i] = atomicAdd(&cnt[eb[i]], 1);
        }
    }
    __syncthreads();

    // phase 2: exclusive scan of cnt -> base
    int loc = 0;
#pragma unroll
    for (int j = 0; j < BPT; ++j) {
        int b = tid * BPT + j;
        base[b] = loc;
        loc += cnt[b];
    }
    ts[tid] = loc;
    __syncthreads();
    for (int off = 1; off < PTHR; off <<= 1) {
        int t = (tid >= off) ? ts[tid - off] : 0;
        __syncthreads();
        ts[tid] += t;
        __syncthreads();
    }
    int tb = ts[tid] - loc;
#pragma unroll
    for (int j = 0; j < BPT; ++j) base[tid * BPT + j] += tb;
    __syncthreads();

    // phase 3: build records (dib packed in w), scatter into LDS
#pragma unroll
    for (int i = 0; i < EPT; ++i) {
        if (ev[i]) {
            int e = tbeg + i * PTHR + tid;
            float4 rq = rel_q[e];
            uint4 u;
            u.x = pack_h2(rq.x, rq.y);
            u.y = pack_h2(rq.z, rq.w);
            u.z = __builtin_bit_cast(unsigned, TEMP * ew[e]);
            u.w = (unsigned)(esrc[e] * KDIM) | ((unsigned)ed[i] << 23);
            int pos = base[eb[i]] + er[i];
            sortbuf[pos] = __builtin_bit_cast(float4, u);
            sbk[pos] = (unsigned short)eb[i];
        }
    }
    __syncthreads();

    // phase 4a: one cursor atomic per bucket -> gpos
    for (int b = tid; b < MAXNB; b += PTHR)
        if (cnt[b]) gpos[b] = atomicAdd(&gcursor[b], cnt[b]);
    __syncthreads();

    // phase 4b: LANE-COALESCED flush
    for (int pos = tid; pos < tcnt; pos += PTHR) {
        int b = sbk[pos];
        ebuf[gpos[b] + (pos - base[b])] = sortbuf[pos];
    }
}

// ===== K4 (fused fine+agg): one block per bucket; LDS float accumulators =====
// acc[128 nodes][8 k][6 comps] = 24 KB. Edges stream from the bucket-sorted
// ebuf window (coalesced); per edge the 8 k-lanes gather ONE qltab line and
// ds_add_f32 into acc. Finalize adds self term + normalizes. No payload
// round-trip, no deg/offs, no overflow cap.
__global__ void __launch_bounds__(256, 4)
agg_bucket(const float* __restrict__ levels,
           const float4* __restrict__ node_q,
           const unsigned long long* __restrict__ qltab,
           const int* __restrict__ gbase,
           const float4* __restrict__ ebuf,
           float4* __restrict__ out_q,
           float* __restrict__ out_lvl, int N) {
    __shared__ float acc[BKT_NODES * KDIM * 6];   // 24 KB
    int bk = blockIdx.x;
    int tid = threadIdx.x;
    int beg = gbase[bk], end = gbase[bk + 1];

    for (int i = tid; i < BKT_NODES * KDIM * 6; i += 256) acc[i] = 0.f;
    __syncthreads();

    int k = tid & 7;
    int seg = tid >> 3;              // 0..31 across the block's 4 waves
    const float QS = 1.0f / 4095.0f;

    for (int j0 = beg + seg; j0 < end; j0 += 32 * 6) {
        float4 pe[6];
        bool v[6];
#pragma unroll
        for (int s = 0; s < 6; ++s) {           // phase 1: independent loads (coalesced)
            int j = j0 + s * 32;
            v[s] = (j < end);
            if (v[s]) pe[s] = ebuf[j];
        }
        unsigned long long g[6];
#pragma unroll
        for (int s = 0; s < 6; ++s)             // phase 2: independent gathers (1 line/edge)
            if (v[s]) {
                unsigned w = __builtin_bit_cast(uint4, pe[s]).w;
                g[s] = qltab[(int)(w & SRC_MASK) + k];
            }
#pragma unroll
        for (int s = 0; s < 6; ++s)             // phase 3: compute + LDS atomics
            if (v[s]) {
                uint4 pu = __builtin_bit_cast(uint4, pe[s]);
                float2 r01 = unpack_h2(pu.x);   // (w,x)
                float2 r23 = unpack_h2(pu.y);   // (y,z)
                float tw = __builtin_bit_cast(float, pu.z);
                int dib = (int)(pu.w >> 23);
                unsigned long long p = g[s];
                float ls = (float)(unsigned)(p & 0xFFFu) * QS;
                float qw = (float)sext13((unsigned)((p >> 12) & 0x1FFFu)) * QS;
                float qx = (float)sext13((unsigned)((p >> 25) & 0x1FFFu)) * QS;
                float qy = (float)sext13((unsigned)((p >> 38) & 0x1FFFu)) * QS;
                float qz = (float)sext13((unsigned)((p >> 51) & 0x1FFFu)) * QS;
                float ex = __expf(tw * ls - MSHIFT);
                float rw = r01.x, rx = r01.y, ry = r23.x, rz = r23.y;
                float* a = &acc[(dib * KDIM + k) * 6];
                atomicAdd(a + 0, ex);
                atomicAdd(a + 1, ex * ls);
                atomicAdd(a + 2, ex * (rw * qw - rx * qx - ry * qy - rz * qz));
                atomicAdd(a + 3, ex * (rw * qx + rx * qw + ry * qz - rz * qy));
                atomicAdd(a + 4, ex * (rw * qy - rx * qz + ry * qw + rz * qx));
                atomicAdd(a + 5, ex * (rw * qz + rx * qy - ry * qx + rz * qw));
            }
    }
    __syncthreads();

    // finalize: 1024 (node,k) tasks, 4 per thread; self term + normalize
    int base_n = bk << BKT_SHIFT;
    for (int t = tid; t < BKT_NODES * KDIM; t += 256) {
        int node = t >> 3, kk = t & 7;
        int n = base_n + node;
        if (n >= N) continue;
        const float* a = &acc[t * 6];
        float den = a[0], lv = a[1], aw = a[2], ax = a[3], ay = a[4], az = a[5];
        int i = n * KDIM + kk;
        float l = levels[i];
        float es = __expf(TEMP * l - MSHIFT);
        den += es;
        lv += es * l;
        float4 q0 = node_q[i];
        aw += es * q0.x; ax += es * q0.y; ay += es * q0.z; az += es * q0.w;
        float inv = 1.0f / den;
        lv *= inv; aw *= inv; ax *= inv; ay *= inv; az *= inv;
        float nn = sqrtf(aw * aw + ax * ax + ay * ay + az * az);
        nn = fmaxf(nn, 1e-12f);
        float rn = 1.0f / nn;
        float4 o;
        o.x = aw * rn; o.y = ax * rn; o.z = ay * rn; o.w = az * rn;
        out_q[i] = o;
        out_lvl[i] = lv;
    }
}

// ================= fallback path (round-3 CSR pipeline, f32 payload) =================

__global__ void rank_kernel(const int* __restrict__ edst, int* __restrict__ deg,
                            int* __restrict__ rank, int E) {
    int e = blockIdx.x * blockDim.x + threadIdx.x;
    if (e < E) rank[e] = atomicAdd(&deg[edst[e]], 1);
}

__global__ void scan1(const int* __restrict__ deg, int* __restrict__ offs,
                      int* __restrict__ bsum, int N) {
    __shared__ int s[256];
    int i = blockIdx.x * 256 + threadIdx.x;
    int v = (i < N) ? deg[i] : 0;
    s[threadIdx.x] = v;
    __syncthreads();
    for (int off = 1; off < 256; off <<= 1) {
        int t = (threadIdx.x >= off) ? s[threadIdx.x - off] : 0;
        __syncthreads();
        s[threadIdx.x] += t;
        __syncthreads();
    }
    if (i < N) offs[i] = s[threadIdx.x] - v;
    if (threadIdx.x == 255) bsum[blockIdx.x] = s[255];
}

__global__ void scan2(int* __restrict__ bsum, int nb) {
    __shared__ int s[1024];
    __shared__ int carry_s;
    if (threadIdx.x == 0) carry_s = 0;
    __syncthreads();
    for (int base = 0; base < nb; base += 1024) {
        int idx = base + threadIdx.x;
        int v = (idx < nb) ? bsum[idx] : 0;
        s[threadIdx.x] = v;
        __syncthreads();
        for (int off = 1; off < 1024; off <<= 1) {
            int t = (threadIdx.x >= off) ? s[threadIdx.x - off] : 0;
            __syncthreads();
            s[threadIdx.x] += t;
            __syncthreads();
        }
        if (idx < nb) bsum[idx] = s[threadIdx.x] - v + carry_s;
        __syncthreads();
        if (threadIdx.x == 0) carry_s += s[1023];
        __syncthreads();
    }
}

__global__ void scan3(int* __restrict__ offs, const int* __restrict__ bsum,
                      int N, int E) {
    int i = blockIdx.x * 256 + threadIdx.x;
    if (i < N) offs[i] += bsum[blockIdx.x];
    if (i == 0) offs[N] = E;
}

__global__ void permute_kernel(const int* __restrict__ edst,
                               const int* __restrict__ rank,
                               const int* __restrict__ offs,
                               const float4* __restrict__ rel_q,
                               const float* __restrict__ ew,
                               const int* __restrict__ esrc,
                               float4* __restrict__ payload, int E) {
    int e = blockIdx.x * blockDim.x + threadIdx.x;
    if (e >= E) return;
    int pos = offs[edst[e]] + rank[e];
    payload[2 * pos] = rel_q[e];
    float4 m;
    m.x = TEMP * ew[e];
    m.y = __int_as_float(esrc[e] * KDIM);
    m.z = 0.0f; m.w = 0.0f;
    payload[2 * pos + 1] = m;
}

__global__ void agg_payload(const float* __restrict__ levels,
                            const float4* __restrict__ node_q,
                            const int* __restrict__ offs,
                            const float4* __restrict__ payload,
                            float4* __restrict__ out_q,
                            float* __restrict__ out_lvl, int N) {
    int t = blockIdx.x * blockDim.x + threadIdx.x;
    int n = t >> 3;
    int k = t & 7;
    if (n >= N) return;
    int i = n * KDIM + k;
    float l = levels[i];
    float es = __expf(TEMP * l - MSHIFT);
    float den = es, lv = es * l;
    float4 q0 = node_q[i];
    float aw = es * q0.x, ax = es * q0.y, ay = es * q0.z, az = es * q0.w;
    int beg = offs[n], end = offs[n + 1];
#pragma unroll 2
    for (int j = beg; j < end; j++) {
        float4 r = payload[2 * j];
        float4 m = payload[2 * j + 1];
        float tw = m.x;
        int src8 = __float_as_int(m.y);
        float ls = levels[src8 + k];
        float ex = __expf(tw * ls - MSHIFT);
        float4 q = node_q[src8 + k];
        den += ex;
        lv += ex * ls;
        aw += ex * (r.x * q.x - r.y * q.y - r.z * q.z - r.w * q.w);
        ax += ex * (r.x * q.y + r.y * q.x + r.z * q.w - r.w * q.z);
        ay += ex * (r.x * q.z - r.y * q.w + r.z * q.x + r.w * q.y);
        az += ex * (r.x * q.w + r.y * q.z - r.z * q.y + r.w * q.x);
    }
    float inv = 1.0f / den;
    lv *= inv; aw *= inv; ax *= inv; ay *= inv; az *= inv;
    float nn = sqrtf(aw * aw + ax * ax + ay * ay + az * az);
    nn = fmaxf(nn, 1e-12f);
    float rn = 1.0f / nn;
    float4 o;
    o.x = aw * rn; o.y = ax * rn; o.z = ay * rn; o.w = az * rn;
    out_q[i] = o;
    out_lvl[i] = lv;
}

extern "C" void kernel_launch(void* const* d_in, const int* in_sizes, int n_in,
                              void* d_out, int out_size, void* d_ws, size_t ws_size,
                              hipStream_t stream) {
    const float*  levels = (const float*)d_in[0];   // [N,K]
    const float4* node_q = (const float4*)d_in[1];  // [N,K,4]
    const float4* rel_q  = (const float4*)d_in[2];  // [E,4]
    const float*  ew     = (const float*)d_in[3];   // [E]
    const int*    esrc   = (const int*)d_in[4];     // [E]
    const int*    edst   = (const int*)d_in[5];     // [E]

    const int NK = in_sizes[0];
    const int E  = in_sizes[3];
    const int N  = NK / KDIM;
    const int B  = 256;
    const int gE = (E + B - 1) / B;
    const int gN = (NK + B - 1) / B;

    float* out_q   = (float*)d_out;
    float* out_lvl = (float*)d_out + (size_t)NK * 4;

    // ---- primary layout: ghist | gbase | gcursor | qltab | ebuf ----
    const int NBKT = (N + BKT_NODES - 1) >> BKT_SHIFT;
    const int HB   = (E + EPB_H - 1) / EPB_H;
    auto al = [](size_t x) { return (x + 255) & ~(size_t)255; };
    size_t o_ghist = 0;
    size_t o_gbase = o_ghist + al((size_t)MAXNB * 4);
    size_t o_gcur  = o_gbase + al((size_t)(MAXNB + 1) * 4);
    size_t o_qltab = o_gcur  + al((size_t)MAXNB * 4);
    size_t o_ebuf  = o_qltab + al((size_t)NK * 8);
    size_t need    = o_ebuf  + al((size_t)E * 16);

    if (NBKT <= MAXNB && ws_size >= need && N < (1 << 20) / KDIM * 8) {
        int* ghist   = (int*)((char*)d_ws + o_ghist);
        int* gbase   = (int*)((char*)d_ws + o_gbase);
        int* gcursor = (int*)((char*)d_ws + o_gcur);
        unsigned long long* qltab = (unsigned long long*)((char*)d_ws + o_qltab);
        float4* ebuf = (float4*)((char*)d_ws + o_ebuf);

        (void)hipMemsetAsync(ghist, 0, (size_t)MAXNB * 4, stream);
        prep_hist<<<gN + HB, B, 0, stream>>>(levels, node_q, qltab, NK, gN,
                                             edst, ghist, E);
        scan_buckets<<<1, 1024, 0, stream>>>(ghist, gbase, gcursor, NBKT, E);
        int PB = (E + TILE - 1) / TILE;
        partition_lds<<<PB, PTHR, 0, stream>>>(edst, esrc, ew, rel_q, gcursor,
                                               ebuf, E);
        agg_bucket<<<NBKT, B, 0, stream>>>(levels, node_q, qltab, gbase, ebuf,
                                           (float4*)out_q, out_lvl, N);
        return;
    }

    // ---- fallback: round-3 CSR pipeline ----
    const int nb = (N + 255) / 256;
    int* deg  = (int*)d_ws;
    int* offs = deg + N;
    int* bsum = offs + N + 1;
    size_t prefix = (size_t)(2 * N + 1 + nb);
    int* rank = bsum + nb;
    size_t pay_off = (prefix + E + 3) & ~(size_t)3;
    float4* payload = (float4*)((int*)d_ws + pay_off);

    (void)hipMemsetAsync(deg, 0, (size_t)N * sizeof(int), stream);
    rank_kernel<<<gE, B, 0, stream>>>(edst, deg, rank, E);
    scan1<<<nb, 256, 0, stream>>>(deg, offs, bsum, N);
    scan2<<<1, 1024, 0, stream>>>(bsum, nb);
    scan3<<<nb, 256, 0, stream>>>(offs, bsum, N, E);
    permute_kernel<<<gE, B, 0, stream>>>(edst, rank, offs, rel_q, ew, esrc,
                                         payload, E);
    agg_payload<<<gN, B, 0, stream>>>(levels, node_q, offs, payload,
                                      (float4*)out_q, out_lvl, N);
}